// Round 13
// baseline (377.492 us; speedup 1.0000x reference)
//
#include <hip/hip_runtime.h>

#define N_NODES 50000
#define N_EDGES 600000
#define N_RELS  19
#define D_IN    128
#define D_HID   64
#define D_OUT   2
#define EDGE_TILES ((N_EDGES + 127) / 128 + N_RELS)   // 4707
#define SL_BLOCKS  ((N_NODES + 63) / 64)              // 782

typedef unsigned short u16;
typedef unsigned int   u32;
typedef __attribute__((ext_vector_type(8))) short sfrag;   // 8 bf16 (4 VGPRs)
typedef __attribute__((ext_vector_type(4))) float f32x4;   // 4 fp32 acc

__device__ __forceinline__ u16 f2bf(float f){
  union { float f; u32 i; } v; v.f = f;
  u32 r = v.i + 0x7fffu + ((v.i >> 16) & 1u);  // RNE
  return (u16)(r >> 16);
}
__device__ __forceinline__ float bf2f(u16 u){
  union { u32 i; float f; } v; v.i = ((u32)u) << 16; return v.f;
}

// Weights -> bf16; zero hist_rel, hist_dst, gcnt.
// W1Tb [19][64][128]; loop1Tb [64][128];
// W2T2b [48][64]: rows 0..37 = W2[r][:,k] (j=2r+k), rows 38/39 = loop2[:,k], 40..47 = 0.
__global__ void k_prep(const float* __restrict__ W1, const float* __restrict__ loop1,
                       const float* __restrict__ W2, const float* __restrict__ loop2,
                       u16* __restrict__ W1Tb, u16* __restrict__ loop1Tb,
                       u16* __restrict__ W2T2b, int* __restrict__ hist_rel,
                       int* __restrict__ hist_dst, int* __restrict__ gcnt){
  int idx = blockIdx.x * 256 + threadIdx.x;
  if (idx < N_RELS)  hist_rel[idx] = 0;
  if (idx < N_NODES) hist_dst[idx] = 0;
  if (idx == 0) gcnt[0] = 0;
  const int T1 = N_RELS * D_HID * D_IN;        // 155648
  const int T2 = T1 + 48 * D_HID;              // +3072
  const int T3 = T2 + D_HID * D_IN;            // +8192 = 166912
  if (idx < T1) {
    int r = idx / (D_HID * D_IN);
    int t = idx - r * (D_HID * D_IN);
    int j = t >> 7, d = t & 127;
    W1Tb[idx] = f2bf(W1[(r * D_IN + d) * D_HID + j]);
  } else if (idx < T2) {
    int k2 = idx - T1;
    int j = k2 >> 6, d = k2 & 63;
    float v = 0.f;
    if (j < 2 * N_RELS)          v = W2[((j >> 1) * D_HID + d) * D_OUT + (j & 1)];
    else if (j < 2 * N_RELS + 2) v = loop2[d * D_OUT + (j - 2 * N_RELS)];
    W2T2b[k2] = f2bf(v);
  } else if (idx < T3) {
    int k2 = idx - T2;
    int j = k2 >> 7, d = k2 & 127;
    loop1Tb[k2] = f2bf(loop1[d * D_HID + j]);
  }
}

// Fused: feat->featb bf16 convert, rel histogram, dst histogram.
__global__ __launch_bounds__(256) void k_fused_pre(const float* __restrict__ feat,
                                                   u16* __restrict__ featb,
                                                   const int* __restrict__ et,
                                                   const int* __restrict__ dst,
                                                   int* __restrict__ hist_rel,
                                                   int* __restrict__ hist_dst){
  int i = blockIdx.x * 256 + threadIdx.x;
  float2 f = ((const float2*)feat)[i];
  ((u32*)featb)[i] = (u32)f2bf(f.x) | ((u32)f2bf(f.y) << 16);
  if (blockIdx.x < (N_EDGES + 255) / 256) {      // block-uniform branch
    __shared__ int lh[N_RELS];
    int tid = threadIdx.x;
    if (tid < N_RELS) lh[tid] = 0;
    __syncthreads();
    int e = blockIdx.x * 256 + tid;
    if (e < N_EDGES) {
      atomicAdd(&lh[et[e]], 1);
      atomicAdd(&hist_dst[dst[e]], 1);
    }
    __syncthreads();
    if (tid < N_RELS && lh[tid]) atomicAdd(&hist_rel[tid], lh[tid]);
  }
}

// Blocks 0..195: msgbuf region allocation (wave prefix + one atomic per wave).
// Block 196: rel scan (offs/toff/cur_rel).
__global__ __launch_bounds__(256) void k_alloc_scan(
    const int* __restrict__ hist_dst, int* __restrict__ dstart,
    int* __restrict__ cur_dst, int* __restrict__ gcnt,
    const int* __restrict__ hist_rel, int* __restrict__ offs,
    int* __restrict__ toff, int* __restrict__ cur_rel){
  if (blockIdx.x == 196) {
    if (threadIdx.x == 0) {
      int acc = 0, tacc = 0;
      offs[0] = 0; toff[0] = 0;
      for (int r = 0; r < N_RELS; ++r) {
        cur_rel[r] = acc;
        int c = hist_rel[r];
        acc += c;                offs[r + 1] = acc;
        tacc += (c + 127) >> 7;  toff[r + 1] = tacc;
      }
    }
    return;
  }
  __shared__ int wbase[4];
  int tid = threadIdx.x, lane = tid & 63, wv = tid >> 6;
  int n = blockIdx.x * 256 + tid;
  int v = (n < N_NODES) ? hist_dst[n] : 0;
  int x = v;
  #pragma unroll
  for (int o = 1; o < 64; o <<= 1) { int u = __shfl_up(x, o); if (lane >= o) x += u; }
  if (lane == 63) wbase[wv] = atomicAdd(gcnt, x);   // x = wave total
  __syncthreads();
  int start = wbase[wv] + x - v;
  if (n < N_NODES) { dstart[n] = start; cur_dst[n] = start; }
}

__global__ __launch_bounds__(256) void k_scatter_rel(const int* __restrict__ et,
                                                     int* __restrict__ cursor,
                                                     int* __restrict__ perm){
  __shared__ int lh[N_RELS], base[N_RELS];
  int tid = threadIdx.x;
  if (tid < N_RELS) lh[tid] = 0;
  __syncthreads();
  int e = blockIdx.x * 256 + tid;
  int r = 0, my = 0;
  bool valid = e < N_EDGES;
  if (valid) { r = et[e]; my = atomicAdd(&lh[r], 1); }
  __syncthreads();
  if (tid < N_RELS && lh[tid]) base[tid] = atomicAdd(&cursor[tid], lh[tid]);
  __syncthreads();
  if (valid) perm[base[r] + my] = e;
}

// Merged: blocks < EDGE_TILES run layer-1 edge tiles (128 edges, K=128 bf16 MFMA,
// B staged in LDS, messages -> msgbuf rows). Blocks >= EDGE_TILES run the dense
// self-loop GEMM (agg1f = feat @ loop1 + b1), also with B staged in LDS.
__global__ __launch_bounds__(256) void k_se1(
    const u16* __restrict__ featb, const u16* __restrict__ W1Tb,
    const u16* __restrict__ loop1Tb, const float* __restrict__ b1,
    const int* __restrict__ src, const int* __restrict__ dst,
    const int* __restrict__ perm, const int* __restrict__ offs,
    const int* __restrict__ toff, int* __restrict__ cur_dst,
    u16* __restrict__ msgbuf, float* __restrict__ agg1f){
  __shared__ __align__(16) u16 Als[128][136];   // 34816 B; overlaid by msg fp32 [128][68]
  __shared__ __align__(16) u16 Bls[64][136];    // 17408 B
  __shared__ int posIds[128];
  int tid = threadIdx.x, lane = tid & 63, w = tid >> 6;
  int r16 = lane & 15, c4 = lane >> 4;

  if (blockIdx.x >= EDGE_TILES) {               // ---- self-loop path ----
    int base = (blockIdx.x - EDGE_TILES) * 64;
    { int j = tid >> 2, seg = tid & 3;
      const uint4* g = (const uint4*)(loop1Tb + j * 128) + seg * 4;
      uint4* d = (uint4*)&Bls[j][seg * 32];
      d[0] = g[0]; d[1] = g[1]; d[2] = g[2]; d[3] = g[3]; }
    { int i = tid >> 2, seg = tid & 3;
      int n = base + i; if (n >= N_NODES) n = N_NODES - 1;
      const uint4* g = (const uint4*)(featb + (size_t)n * D_IN) + seg * 4;
      uint4* d = (uint4*)&Als[i][seg * 32];
      d[0] = g[0]; d[1] = g[1]; d[2] = g[2]; d[3] = g[3]; }
    __syncthreads();
    sfrag aF[4];
    #pragma unroll
    for (int kk = 0; kk < 4; ++kk)
      aF[kk] = *(const sfrag*)&Als[w * 16 + r16][kk * 32 + c4 * 8];
    #pragma unroll
    for (int ct = 0; ct < 4; ++ct) {
      f32x4 acc = {0.f, 0.f, 0.f, 0.f};
      #pragma unroll
      for (int kk = 0; kk < 4; ++kk) {
        sfrag bF = *(const sfrag*)&Bls[ct * 16 + r16][kk * 32 + c4 * 8];
        acc = __builtin_amdgcn_mfma_f32_16x16x32_bf16(aF[kk], bF, acc, 0, 0, 0);
      }
      int col = ct * 16 + r16;
      float bias = b1[col];
      #pragma unroll
      for (int reg = 0; reg < 4; ++reg) {
        int row = base + w * 16 + c4 * 4 + reg;
        if (row < N_NODES) agg1f[(size_t)row * D_HID + col] = acc[reg] + bias;
      }
    }
    return;
  }

  // ---- edge-tile path ----
  int b = blockIdx.x;
  unsigned long long mm = __ballot((lane < N_RELS) && (b >= toff[lane + 1]));
  int rel = __popcll(mm);
  if (rel >= N_RELS) return;                    // uniform pad-tile exit
  int ts = offs[rel] + ((b - toff[rel]) << 7);
  int vc = offs[rel + 1] - ts; if (vc > 128) vc = 128;

  { // B tile: W1Tb[rel], 64 x 128 bf16 (16 KB)
    int j = tid >> 2, seg = tid & 3;
    const uint4* g = (const uint4*)(W1Tb + ((size_t)rel * 64 + j) * 128) + seg * 4;
    uint4* d = (uint4*)&Bls[j][seg * 32];
    d[0] = g[0]; d[1] = g[1]; d[2] = g[2]; d[3] = g[3];
  }
  // A tile: 128 rows x 256 B, 2 passes, 4 threads/row
  #pragma unroll
  for (int p = 0; p < 2; ++p) {
    int i = p * 64 + (tid >> 2), seg = tid & 3;
    if (i < vc) {
      int e = perm[ts + i];
      if (seg == 0) posIds[i] = atomicAdd(&cur_dst[dst[e]], 1);  // absolute msg row
      const uint4* g = (const uint4*)(featb + (size_t)src[e] * D_IN) + seg * 4;
      uint4* d = (uint4*)&Als[i][seg * 32];
      d[0] = g[0]; d[1] = g[1]; d[2] = g[2]; d[3] = g[3];
    } else if (seg == 0) posIds[i] = -1;
  }
  __syncthreads();

  sfrag aF[2][4];
  #pragma unroll
  for (int mt = 0; mt < 2; ++mt)
    #pragma unroll
    for (int kk = 0; kk < 4; ++kk)
      aF[mt][kk] = *(const sfrag*)&Als[w * 32 + mt * 16 + r16][kk * 32 + c4 * 8];
  f32x4 accAll[2][4];
  #pragma unroll
  for (int ct = 0; ct < 4; ++ct) {
    sfrag bF[4];
    #pragma unroll
    for (int kk = 0; kk < 4; ++kk)
      bF[kk] = *(const sfrag*)&Bls[ct * 16 + r16][kk * 32 + c4 * 8];
    #pragma unroll
    for (int mt = 0; mt < 2; ++mt) {
      f32x4 acc = {0.f, 0.f, 0.f, 0.f};
      #pragma unroll
      for (int kk = 0; kk < 4; ++kk)
        acc = __builtin_amdgcn_mfma_f32_16x16x32_bf16(aF[mt][kk], bF[kk], acc, 0, 0, 0);
      accAll[mt][ct] = acc;
    }
  }
  // msg overlay (wave-private rows), then coalesced bf16 row write-out
  float* msg = (float*)&Als[0][0];              // stride 68 floats == 272 B == Als row
  #pragma unroll
  for (int mt = 0; mt < 2; ++mt)
    #pragma unroll
    for (int ct = 0; ct < 4; ++ct) {
      int col = ct * 16 + r16;
      #pragma unroll
      for (int reg = 0; reg < 4; ++reg) {
        int row = w * 32 + mt * 16 + c4 * 4 + reg;   // D: col=lane&15, row=(lane>>4)*4+reg
        msg[row * 68 + col] = accAll[mt][ct][reg];
      }
    }
  __syncthreads();
  { int row = tid >> 1, half = tid & 1;
    int pos = posIds[row];
    if (pos >= 0) {
      const float* mr = msg + row * 68 + half * 32;
      u32 pk[16];
      #pragma unroll
      for (int q = 0; q < 16; ++q)
        pk[q] = (u32)f2bf(mr[2 * q]) | ((u32)f2bf(mr[2 * q + 1]) << 16);
      uint4* d = (uint4*)(msgbuf + (size_t)pos * D_HID + half * 32);
      d[0] = *(uint4*)&pk[0];  d[1] = *(uint4*)&pk[4];
      d[2] = *(uint4*)&pk[8];  d[3] = *(uint4*)&pk[12];
    } }
}

// Fused: message aggregation (ONE NODE PER WAVE) + self-loop + relu -> h1 (registers),
// then per-node T row: T[n][j] = h1[n] . W2T2b[j] (j=0..39; 38/39 init out with b2).
__global__ __launch_bounds__(256) void k_agg_T(
    const u16* __restrict__ msgbuf, const int* __restrict__ dstart,
    const int* __restrict__ cnt, const float* __restrict__ agg1f,
    const u16* __restrict__ W2T2b, const float* __restrict__ b2,
    float* __restrict__ Tmat, float* __restrict__ out){
  __shared__ u32 Wls[48 * 33];                 // padded rows: row j at j*33 (2-way conflict max)
  int tid = threadIdx.x, wv = tid >> 6, lane = tid & 63;
  #pragma unroll
  for (int p = 0; p < 6; ++p) {               // stage 1536 u32 coalesced
    int idx = p * 256 + tid;
    Wls[(idx >> 5) * 33 + (idx & 31)] = ((const u32*)W2T2b)[idx];
  }
  int n = blockIdx.x * 4 + wv;                // grid covers exactly N_NODES
  int s = dstart[n], epos = s + cnt[n];
  int h = lane >> 5, c = lane & 31;
  float a0 = 0.f, a1 = 0.f;
  for (int i = s + h; i < epos; i += 2) {
    u32 v = ((const u32*)msgbuf)[(size_t)i * 32 + c];
    a0 += bf2f((u16)(v & 0xffffu));
    a1 += bf2f((u16)(v >> 16));
  }
  a0 += __shfl_down(a0, 32);                  // valid in lanes 0..31
  a1 += __shfl_down(a1, 32);
  float2 sl = ((const float2*)(agg1f + (size_t)n * D_HID))[c];
  float v0 = a0 + sl.x, v1 = a1 + sl.y;       // lane c: h1[2c], h1[2c+1] (lanes>=32 garbage, never sourced)
  v0 = v0 > 0.f ? v0 : 0.f;
  v1 = v1 > 0.f ? v1 : 0.f;
  __syncthreads();                            // Wls ready
  int row = lane < 48 ? lane : 0;             // lanes 48..63 compute a dummy row
  const u32* wr = &Wls[row * 33];
  float acc = 0.f;
  #pragma unroll
  for (int q = 0; q < 32; ++q) {
    float h0  = __shfl(v0, q);                // h1[2q]
    float h1v = __shfl(v1, q);                // h1[2q+1]
    u32 wp = wr[q];
    acc += h0 * bf2f((u16)(wp & 0xffffu)) + h1v * bf2f((u16)(wp >> 16));
  }
  if (lane < 40) {
    Tmat[(size_t)n * 40 + lane] = acc;
    if (lane >= 38) out[n * 2 + (lane - 38)] = acc + b2[lane - 38];  // self2 + bias, full init
  }
}

// Layer-2 edge scatter: out[dst] += T[src][2*et + k], one thread per edge.
__global__ __launch_bounds__(256) void k_edge2s(const int* __restrict__ src,
                                                const int* __restrict__ dst,
                                                const int* __restrict__ et,
                                                const float* __restrict__ Tmat,
                                                float* __restrict__ out){
  int e = blockIdx.x * 256 + threadIdx.x;
  if (e < N_EDGES) {
    float2 tv = *(const float2*)(Tmat + (size_t)src[e] * 40 + 2 * et[e]);
    int d = dst[e];
    atomicAdd(&out[d * 2],     tv.x);
    atomicAdd(&out[d * 2 + 1], tv.y);
  }
}

extern "C" void kernel_launch(void* const* d_in, const int* in_sizes, int n_in,
                              void* d_out, int out_size, void* d_ws, size_t ws_size,
                              hipStream_t stream){
  const float* feat  = (const float*)d_in[0];
  const float* W1    = (const float*)d_in[1];
  const float* loop1 = (const float*)d_in[2];
  const float* b1    = (const float*)d_in[3];
  const float* W2    = (const float*)d_in[4];
  const float* loop2 = (const float*)d_in[5];
  const float* b2    = (const float*)d_in[6];
  const int* src     = (const int*)d_in[7];
  const int* dst     = (const int*)d_in[8];
  const int* et      = (const int*)d_in[9];
  float* out = (float*)d_out;

  // workspace layout (16B-aligned), ~114 MB total
  char* w = (char*)d_ws;
  u16*   W1Tb     = (u16*)(w);                   //  311296
  u16*   W2T2b    = (u16*)(w + 311296);          //    6144
  u16*   loop1Tb  = (u16*)(w + 317440);          //   16384
  int*   hist_rel = (int*)(w + 333824);          //     128
  int*   offs     = (int*)(w + 333952);
  int*   toff     = (int*)(w + 334080);
  int*   cur_rel  = (int*)(w + 334208);
  int*   gcnt     = (int*)(w + 334336);          //     128
  int*   hist_dst = (int*)(w + 334464);          //  200000
  int*   dstart   = (int*)(w + 534464);          //  200000
  int*   cur_dst  = (int*)(w + 734464);          //  200000
  int*   perm     = (int*)(w + 934464);          // 2400000
  u16*   featb    = (u16*)(w + 3334464);         // 12.8 MB
  float* agg1f    = (float*)(w + 16134464);      // 12.8 MB
  float* Tmat     = (float*)(w + 28934464);      //  8.0 MB
  u16*   msgbuf   = (u16*)(w + 36934464);        // 76.8 MB -> 113734464

  k_prep       <<<652,   256, 0, stream>>>(W1, loop1, W2, loop2, W1Tb, loop1Tb, W2T2b,
                                           hist_rel, hist_dst, gcnt);
  k_fused_pre  <<<12500, 256, 0, stream>>>(feat, featb, et, dst, hist_rel, hist_dst);
  k_alloc_scan <<<197,   256, 0, stream>>>(hist_dst, dstart, cur_dst, gcnt,
                                           hist_rel, offs, toff, cur_rel);
  k_scatter_rel<<<2344,  256, 0, stream>>>(et, cur_rel, perm);
  k_se1        <<<EDGE_TILES + SL_BLOCKS, 256, 0, stream>>>(
                   featb, W1Tb, loop1Tb, b1, src, dst, perm, offs, toff,
                   cur_dst, msgbuf, agg1f);
  k_agg_T      <<<12500, 256, 0, stream>>>(msgbuf, dstart, hist_dst, agg1f,
                                           W2T2b, b2, Tmat, out);
  k_edge2s     <<<2344,  256, 0, stream>>>(src, dst, et, Tmat, out);
}

// Round 14
// 319.872 us; speedup vs baseline: 1.1801x; 1.1801x over previous
//
#include <hip/hip_runtime.h>

#define N_NODES 50000
#define N_EDGES 600000
#define N_RELS  19
#define D_IN    128
#define D_HID   64
#define D_OUT   2
#define EDGE_TILES ((N_EDGES + 127) / 128 + N_RELS)   // 4707
#define SL_BLOCKS  ((N_NODES + 63) / 64)              // 782

typedef unsigned short u16;
typedef unsigned int   u32;
typedef __attribute__((ext_vector_type(8))) short sfrag;   // 8 bf16 (4 VGPRs)
typedef __attribute__((ext_vector_type(4))) float f32x4;   // 4 fp32 acc

__device__ __forceinline__ u16 f2bf(float f){
  union { float f; u32 i; } v; v.f = f;
  u32 r = v.i + 0x7fffu + ((v.i >> 16) & 1u);  // RNE
  return (u16)(r >> 16);
}
__device__ __forceinline__ float bf2f(u16 u){
  union { u32 i; float f; } v; v.i = ((u32)u) << 16; return v.f;
}

// Weights -> bf16 transposed; zero hist_rel, hist_dst, gcnt.
// W1Tb [19][64][128]; W2Tb [19][16][64] (cols>=2 zero); loop1Tb [64][128].
__global__ void k_prep(const float* __restrict__ W1, const float* __restrict__ loop1,
                       const float* __restrict__ W2,
                       u16* __restrict__ W1Tb, u16* __restrict__ loop1Tb,
                       u16* __restrict__ W2Tb, int* __restrict__ hist_rel,
                       int* __restrict__ hist_dst, int* __restrict__ gcnt){
  int idx = blockIdx.x * 256 + threadIdx.x;
  if (idx < N_RELS)  hist_rel[idx] = 0;
  if (idx < N_NODES) hist_dst[idx] = 0;
  if (idx == 0) gcnt[0] = 0;
  const int T1 = N_RELS * D_HID * D_IN;        // 155648
  const int T2 = T1 + N_RELS * 16 * D_HID;     // +19456
  const int T3 = T2 + D_HID * D_IN;            // +8192 = 183296
  if (idx < T1) {
    int r = idx / (D_HID * D_IN);
    int t = idx - r * (D_HID * D_IN);
    int j = t >> 7, d = t & 127;
    W1Tb[idx] = f2bf(W1[(r * D_IN + d) * D_HID + j]);
  } else if (idx < T2) {
    int k2 = idx - T1;
    int r = k2 / (16 * D_HID);
    int t = k2 - r * (16 * D_HID);
    int n = t >> 6, k = t & 63;
    W2Tb[k2] = (n < D_OUT) ? f2bf(W2[(r * D_HID + k) * D_OUT + n]) : (u16)0;
  } else if (idx < T3) {
    int k2 = idx - T2;
    int j = k2 >> 7, d = k2 & 127;
    loop1Tb[k2] = f2bf(loop1[d * D_HID + j]);
  }
}

// Fused: feat->featb bf16 convert, rel histogram, dst histogram.
__global__ __launch_bounds__(256) void k_fused_pre(const float* __restrict__ feat,
                                                   u16* __restrict__ featb,
                                                   const int* __restrict__ et,
                                                   const int* __restrict__ dst,
                                                   int* __restrict__ hist_rel,
                                                   int* __restrict__ hist_dst){
  int i = blockIdx.x * 256 + threadIdx.x;
  float2 f = ((const float2*)feat)[i];
  ((u32*)featb)[i] = (u32)f2bf(f.x) | ((u32)f2bf(f.y) << 16);
  if (blockIdx.x < (N_EDGES + 255) / 256) {      // block-uniform branch
    __shared__ int lh[N_RELS];
    int tid = threadIdx.x;
    if (tid < N_RELS) lh[tid] = 0;
    __syncthreads();
    int e = blockIdx.x * 256 + tid;
    if (e < N_EDGES) {
      atomicAdd(&lh[et[e]], 1);
      atomicAdd(&hist_dst[dst[e]], 1);
    }
    __syncthreads();
    if (tid < N_RELS && lh[tid]) atomicAdd(&hist_rel[tid], lh[tid]);
  }
}

// Blocks 0..195: msgbuf region allocation (wave prefix + one atomic per wave).
// Block 196: rel scan (offs/toff/cur_rel).
__global__ __launch_bounds__(256) void k_alloc_scan(
    const int* __restrict__ hist_dst, int* __restrict__ dstart,
    int* __restrict__ cur_dst, int* __restrict__ gcnt,
    const int* __restrict__ hist_rel, int* __restrict__ offs,
    int* __restrict__ toff, int* __restrict__ cur_rel){
  if (blockIdx.x == 196) {
    if (threadIdx.x == 0) {
      int acc = 0, tacc = 0;
      offs[0] = 0; toff[0] = 0;
      for (int r = 0; r < N_RELS; ++r) {
        cur_rel[r] = acc;
        int c = hist_rel[r];
        acc += c;                offs[r + 1] = acc;
        tacc += (c + 127) >> 7;  toff[r + 1] = tacc;
      }
    }
    return;
  }
  __shared__ int wbase[4];
  int tid = threadIdx.x, lane = tid & 63, wv = tid >> 6;
  int n = blockIdx.x * 256 + tid;
  int v = (n < N_NODES) ? hist_dst[n] : 0;
  int x = v;
  #pragma unroll
  for (int o = 1; o < 64; o <<= 1) { int u = __shfl_up(x, o); if (lane >= o) x += u; }
  if (lane == 63) wbase[wv] = atomicAdd(gcnt, x);   // x = wave total
  __syncthreads();
  int start = wbase[wv] + x - v;
  if (n < N_NODES) { dstart[n] = start; cur_dst[n] = start; }
}

__global__ __launch_bounds__(256) void k_scatter_rel(const int* __restrict__ et,
                                                     int* __restrict__ cursor,
                                                     int* __restrict__ perm){
  __shared__ int lh[N_RELS], base[N_RELS];
  int tid = threadIdx.x;
  if (tid < N_RELS) lh[tid] = 0;
  __syncthreads();
  int e = blockIdx.x * 256 + tid;
  int r = 0, my = 0;
  bool valid = e < N_EDGES;
  if (valid) { r = et[e]; my = atomicAdd(&lh[r], 1); }
  __syncthreads();
  if (tid < N_RELS && lh[tid]) base[tid] = atomicAdd(&cursor[tid], lh[tid]);
  __syncthreads();
  if (valid) perm[base[r] + my] = e;
}

// Merged: blocks < EDGE_TILES run layer-1 edge tiles (128 edges, K=128 bf16 MFMA,
// B staged in LDS, messages -> msgbuf rows). Blocks >= EDGE_TILES run the dense
// self-loop GEMM (agg1f = feat @ loop1 + b1), also with B staged in LDS.
__global__ __launch_bounds__(256) void k_se1(
    const u16* __restrict__ featb, const u16* __restrict__ W1Tb,
    const u16* __restrict__ loop1Tb, const float* __restrict__ b1,
    const int* __restrict__ src, const int* __restrict__ dst,
    const int* __restrict__ perm, const int* __restrict__ offs,
    const int* __restrict__ toff, int* __restrict__ cur_dst,
    u16* __restrict__ msgbuf, float* __restrict__ agg1f){
  __shared__ __align__(16) u16 Als[128][136];   // 34816 B; overlaid by msg fp32 [128][68]
  __shared__ __align__(16) u16 Bls[64][136];    // 17408 B
  __shared__ int posIds[128];
  int tid = threadIdx.x, lane = tid & 63, w = tid >> 6;
  int r16 = lane & 15, c4 = lane >> 4;

  if (blockIdx.x >= EDGE_TILES) {               // ---- self-loop path ----
    int base = (blockIdx.x - EDGE_TILES) * 64;
    { int j = tid >> 2, seg = tid & 3;
      const uint4* g = (const uint4*)(loop1Tb + j * 128) + seg * 4;
      uint4* d = (uint4*)&Bls[j][seg * 32];
      d[0] = g[0]; d[1] = g[1]; d[2] = g[2]; d[3] = g[3]; }
    { int i = tid >> 2, seg = tid & 3;
      int n = base + i; if (n >= N_NODES) n = N_NODES - 1;
      const uint4* g = (const uint4*)(featb + (size_t)n * D_IN) + seg * 4;
      uint4* d = (uint4*)&Als[i][seg * 32];
      d[0] = g[0]; d[1] = g[1]; d[2] = g[2]; d[3] = g[3]; }
    __syncthreads();
    sfrag aF[4];
    #pragma unroll
    for (int kk = 0; kk < 4; ++kk)
      aF[kk] = *(const sfrag*)&Als[w * 16 + r16][kk * 32 + c4 * 8];
    #pragma unroll
    for (int ct = 0; ct < 4; ++ct) {
      f32x4 acc = {0.f, 0.f, 0.f, 0.f};
      #pragma unroll
      for (int kk = 0; kk < 4; ++kk) {
        sfrag bF = *(const sfrag*)&Bls[ct * 16 + r16][kk * 32 + c4 * 8];
        acc = __builtin_amdgcn_mfma_f32_16x16x32_bf16(aF[kk], bF, acc, 0, 0, 0);
      }
      int col = ct * 16 + r16;
      float bias = b1[col];
      #pragma unroll
      for (int reg = 0; reg < 4; ++reg) {
        int row = base + w * 16 + c4 * 4 + reg;
        if (row < N_NODES) agg1f[(size_t)row * D_HID + col] = acc[reg] + bias;
      }
    }
    return;
  }

  // ---- edge-tile path ----
  int b = blockIdx.x;
  unsigned long long mm = __ballot((lane < N_RELS) && (b >= toff[lane + 1]));
  int rel = __popcll(mm);
  if (rel >= N_RELS) return;                    // uniform pad-tile exit
  int ts = offs[rel] + ((b - toff[rel]) << 7);
  int vc = offs[rel + 1] - ts; if (vc > 128) vc = 128;

  { // B tile: W1Tb[rel], 64 x 128 bf16 (16 KB)
    int j = tid >> 2, seg = tid & 3;
    const uint4* g = (const uint4*)(W1Tb + ((size_t)rel * 64 + j) * 128) + seg * 4;
    uint4* d = (uint4*)&Bls[j][seg * 32];
    d[0] = g[0]; d[1] = g[1]; d[2] = g[2]; d[3] = g[3];
  }
  // A tile: 128 rows x 256 B, 2 passes, 4 threads/row
  #pragma unroll
  for (int p = 0; p < 2; ++p) {
    int i = p * 64 + (tid >> 2), seg = tid & 3;
    if (i < vc) {
      int e = perm[ts + i];
      if (seg == 0) posIds[i] = atomicAdd(&cur_dst[dst[e]], 1);  // absolute msg row
      const uint4* g = (const uint4*)(featb + (size_t)src[e] * D_IN) + seg * 4;
      uint4* d = (uint4*)&Als[i][seg * 32];
      d[0] = g[0]; d[1] = g[1]; d[2] = g[2]; d[3] = g[3];
    } else if (seg == 0) posIds[i] = -1;
  }
  __syncthreads();

  sfrag aF[2][4];
  #pragma unroll
  for (int mt = 0; mt < 2; ++mt)
    #pragma unroll
    for (int kk = 0; kk < 4; ++kk)
      aF[mt][kk] = *(const sfrag*)&Als[w * 32 + mt * 16 + r16][kk * 32 + c4 * 8];
  f32x4 accAll[2][4];
  #pragma unroll
  for (int ct = 0; ct < 4; ++ct) {
    sfrag bF[4];
    #pragma unroll
    for (int kk = 0; kk < 4; ++kk)
      bF[kk] = *(const sfrag*)&Bls[ct * 16 + r16][kk * 32 + c4 * 8];
    #pragma unroll
    for (int mt = 0; mt < 2; ++mt) {
      f32x4 acc = {0.f, 0.f, 0.f, 0.f};
      #pragma unroll
      for (int kk = 0; kk < 4; ++kk)
        acc = __builtin_amdgcn_mfma_f32_16x16x32_bf16(aF[mt][kk], bF[kk], acc, 0, 0, 0);
      accAll[mt][ct] = acc;
    }
  }
  // msg overlay (wave-private rows), then coalesced bf16 row write-out
  float* msg = (float*)&Als[0][0];              // stride 68 floats == 272 B == Als row
  #pragma unroll
  for (int mt = 0; mt < 2; ++mt)
    #pragma unroll
    for (int ct = 0; ct < 4; ++ct) {
      int col = ct * 16 + r16;
      #pragma unroll
      for (int reg = 0; reg < 4; ++reg) {
        int row = w * 32 + mt * 16 + c4 * 4 + reg;   // D: col=lane&15, row=(lane>>4)*4+reg
        msg[row * 68 + col] = accAll[mt][ct][reg];
      }
    }
  __syncthreads();
  { int row = tid >> 1, half = tid & 1;
    int pos = posIds[row];
    if (pos >= 0) {
      const float* mr = msg + row * 68 + half * 32;
      u32 pk[16];
      #pragma unroll
      for (int q = 0; q < 16; ++q)
        pk[q] = (u32)f2bf(mr[2 * q]) | ((u32)f2bf(mr[2 * q + 1]) << 16);
      uint4* d = (uint4*)(msgbuf + (size_t)pos * D_HID + half * 32);
      d[0] = *(uint4*)&pk[0];  d[1] = *(uint4*)&pk[4];
      d[2] = *(uint4*)&pk[8];  d[3] = *(uint4*)&pk[12];
    } }
}

// Fused: message aggregation (one node per wave) + self-loop + relu -> h1b,
// plus layer-2 self-loop: out[n,:] = h1 @ loop2 + b2 (full init of out).
__global__ __launch_bounds__(256) void k_agg_relu_self2(
    const u16* __restrict__ msgbuf, const int* __restrict__ dstart,
    const int* __restrict__ cnt, const float* __restrict__ agg1f,
    const float* __restrict__ loop2, const float* __restrict__ b2,
    u16* __restrict__ h1b, float* __restrict__ out){
  int wv = threadIdx.x >> 6, lane = threadIdx.x & 63;
  int n = blockIdx.x * 4 + wv;
  int s = dstart[n], epos = s + cnt[n];
  int h = lane >> 5, c = lane & 31;
  float a0 = 0.f, a1 = 0.f;
  for (int i = s + h; i < epos; i += 2) {
    u32 v = ((const u32*)msgbuf)[(size_t)i * 32 + c];
    a0 += bf2f((u16)(v & 0xffffu));
    a1 += bf2f((u16)(v >> 16));
  }
  a0 += __shfl_down(a0, 32);
  a1 += __shfl_down(a1, 32);
  float p0 = 0.f, p1 = 0.f;
  if (h == 0) {
    float2 sl = ((const float2*)(agg1f + (size_t)n * D_HID))[c];
    float v0 = a0 + sl.x, v1 = a1 + sl.y;
    v0 = v0 > 0.f ? v0 : 0.f;
    v1 = v1 > 0.f ? v1 : 0.f;
    ((u32*)h1b)[(size_t)n * 32 + c] = (u32)f2bf(v0) | ((u32)f2bf(v1) << 16);
    float2 w0 = ((const float2*)loop2)[2 * c];
    float2 w1 = ((const float2*)loop2)[2 * c + 1];
    p0 = v0 * w0.x + v1 * w1.x;
    p1 = v0 * w0.y + v1 * w1.y;
  }
  #pragma unroll
  for (int off = 16; off; off >>= 1) {
    p0 += __shfl_down(p0, off);
    p1 += __shfl_down(p1, off);
  }
  if (lane == 0) {
    out[n * 2]     = p0 + b2[0];
    out[n * 2 + 1] = p1 + b2[1];
  }
}

// Layer-2 edge messages: 128-edge rel-pure tiles, K=64 bf16 MFMA, cheap 2-col atomics.
__global__ __launch_bounds__(256) void k_edge2_mfma(
    const u16* __restrict__ h1b, const u16* __restrict__ W2Tb,
    const int* __restrict__ src, const int* __restrict__ dst,
    const int* __restrict__ perm, const int* __restrict__ offs,
    const int* __restrict__ toff, float* __restrict__ out){
  __shared__ __align__(16) u16 Als[128][72];
  __shared__ __align__(16) u16 Bls[16][72];
  __shared__ int dstIds[128];
  int tid = threadIdx.x, lane = tid & 63, w = tid >> 6;

  int b = blockIdx.x;
  unsigned long long mm = __ballot((lane < N_RELS) && (b >= toff[lane + 1]));
  int rel = __popcll(mm);
  if (rel >= N_RELS) return;
  int ts = offs[rel] + ((b - toff[rel]) << 7);
  int vc = offs[rel + 1] - ts; if (vc > 128) vc = 128;

  if (tid < 128) {   // B tile: 16 x 64 bf16 = 128 uint4
    ((uint4*)&Bls[tid >> 3][0])[tid & 7] = ((const uint4*)(W2Tb + (size_t)rel * 16 * 64))[tid];
  }
  { // A: 128 rows x 128 B, 2 threads/row
    int i = tid >> 1, half = tid & 1;
    if (i < vc) {
      int e = perm[ts + i];
      if (half == 0) dstIds[i] = dst[e];
      const uint4* g = (const uint4*)(h1b + (size_t)src[e] * D_HID) + half * 4;
      uint4* d = (uint4*)&Als[i][half * 32];
      d[0] = g[0]; d[1] = g[1]; d[2] = g[2]; d[3] = g[3];
    } else if (half == 0) dstIds[i] = -1;
  }
  __syncthreads();

  int r16 = lane & 15, c4 = lane >> 4;
  #pragma unroll
  for (int mt = 0; mt < 2; ++mt) {
    f32x4 acc = {0.f, 0.f, 0.f, 0.f};
    #pragma unroll
    for (int kk = 0; kk < 2; ++kk) {
      sfrag aF = *(const sfrag*)&Als[w * 32 + mt * 16 + r16][kk * 32 + c4 * 8];
      sfrag bF = *(const sfrag*)&Bls[r16][kk * 32 + c4 * 8];
      acc = __builtin_amdgcn_mfma_f32_16x16x32_bf16(aF, bF, acc, 0, 0, 0);
    }
    if (r16 < D_OUT) {
      #pragma unroll
      for (int reg = 0; reg < 4; ++reg) {
        int row = w * 32 + mt * 16 + c4 * 4 + reg;
        int dn = dstIds[row];
        if (dn >= 0) atomicAdd(&out[dn * D_OUT + r16], acc[reg]);
      }
    }
  }
}

extern "C" void kernel_launch(void* const* d_in, const int* in_sizes, int n_in,
                              void* d_out, int out_size, void* d_ws, size_t ws_size,
                              hipStream_t stream){
  const float* feat  = (const float*)d_in[0];
  const float* W1    = (const float*)d_in[1];
  const float* loop1 = (const float*)d_in[2];
  const float* b1    = (const float*)d_in[3];
  const float* W2    = (const float*)d_in[4];
  const float* loop2 = (const float*)d_in[5];
  const float* b2    = (const float*)d_in[6];
  const int* src     = (const int*)d_in[7];
  const int* dst     = (const int*)d_in[8];
  const int* et      = (const int*)d_in[9];
  float* out = (float*)d_out;

  // workspace layout (16B-aligned), ~112 MB total
  char* w = (char*)d_ws;
  u16*   W1Tb     = (u16*)(w);                   //  311296
  u16*   W2Tb     = (u16*)(w + 311296);          //   38912
  u16*   loop1Tb  = (u16*)(w + 350208);          //   16384
  int*   hist_rel = (int*)(w + 366592);          //     128
  int*   offs     = (int*)(w + 366720);
  int*   toff     = (int*)(w + 366848);
  int*   cur_rel  = (int*)(w + 366976);
  int*   gcnt     = (int*)(w + 367104);          //     128
  int*   hist_dst = (int*)(w + 367232);          //  200000
  int*   dstart   = (int*)(w + 567232);          //  200000
  int*   cur_dst  = (int*)(w + 767232);          //  200000
  int*   perm     = (int*)(w + 967232);          // 2400000
  u16*   featb    = (u16*)(w + 3367232);         // 12.8 MB
  float* agg1f    = (float*)(w + 16167232);      // 12.8 MB
  u16*   h1b      = (u16*)(w + 28967232);        //  6.4 MB
  u16*   msgbuf   = (u16*)(w + 35367232);        // 76.8 MB -> 112167232

  k_prep          <<<716,   256, 0, stream>>>(W1, loop1, W2, W1Tb, loop1Tb, W2Tb,
                                              hist_rel, hist_dst, gcnt);
  k_fused_pre     <<<12500, 256, 0, stream>>>(feat, featb, et, dst, hist_rel, hist_dst);
  k_alloc_scan    <<<197,   256, 0, stream>>>(hist_dst, dstart, cur_dst, gcnt,
                                              hist_rel, offs, toff, cur_rel);
  k_scatter_rel   <<<2344,  256, 0, stream>>>(et, cur_rel, perm);
  k_se1           <<<EDGE_TILES + SL_BLOCKS, 256, 0, stream>>>(
                      featb, W1Tb, loop1Tb, b1, src, dst, perm, offs, toff,
                      cur_dst, msgbuf, agg1f);
  k_agg_relu_self2<<<12500, 256, 0, stream>>>(msgbuf, dstart, hist_dst, agg1f,
                                              loop2, b2, h1b, out);
  k_edge2_mfma    <<<EDGE_TILES, 256, 0, stream>>>(h1b, W2Tb, src, dst, perm, offs, toff, out);
}

// Round 16
// 317.025 us; speedup vs baseline: 1.1907x; 1.0090x over previous
//
#include <hip/hip_runtime.h>

#define N_NODES 50000
#define N_EDGES 600000
#define N_RELS  19
#define D_IN    128
#define D_HID   64
#define D_OUT   2
#define EDGE_TILES ((N_EDGES + 127) / 128 + N_RELS)   // 4707
#define SL_BLOCKS  ((N_NODES + 63) / 64)              // 782
#define PREP_BLOCKS ((N_RELS * D_HID * D_IN + N_RELS * 16 * D_HID + D_HID * D_IN + 255) / 256)  // 716

typedef unsigned short u16;
typedef unsigned int   u32;
typedef __attribute__((ext_vector_type(8))) short sfrag;   // 8 bf16 (4 VGPRs)
typedef __attribute__((ext_vector_type(4))) float f32x4;   // 4 fp32 acc

__device__ __forceinline__ u16 f2bf(float f){
  union { float f; u32 i; } v; v.f = f;
  u32 r = v.i + 0x7fffu + ((v.i >> 16) & 1u);  // RNE
  return (u16)(r >> 16);
}
__device__ __forceinline__ float bf2f(u16 u){
  union { u32 i; float f; } v; v.i = ((u32)u) << 16; return v.f;
}

// Fused: feat->featb bf16 convert, rel histogram, dst histogram.
// (hists pre-zeroed by hipMemsetAsync on the stream)
__global__ __launch_bounds__(256) void k_fused_pre(const float* __restrict__ feat,
                                                   u16* __restrict__ featb,
                                                   const int* __restrict__ et,
                                                   const int* __restrict__ dst,
                                                   int* __restrict__ hist_rel,
                                                   int* __restrict__ hist_dst){
  int i = blockIdx.x * 256 + threadIdx.x;
  float2 f = ((const float2*)feat)[i];
  ((u32*)featb)[i] = (u32)f2bf(f.x) | ((u32)f2bf(f.y) << 16);
  if (blockIdx.x < (N_EDGES + 255) / 256) {      // block-uniform branch
    __shared__ int lh[N_RELS];
    int tid = threadIdx.x;
    if (tid < N_RELS) lh[tid] = 0;
    __syncthreads();
    int e = blockIdx.x * 256 + tid;
    if (e < N_EDGES) {
      atomicAdd(&lh[et[e]], 1);
      atomicAdd(&hist_dst[dst[e]], 1);
    }
    __syncthreads();
    if (tid < N_RELS && lh[tid]) atomicAdd(&hist_rel[tid], lh[tid]);
  }
}

// Blocks 0..195: msgbuf region allocation (wave prefix + one atomic per wave).
// Block 196: rel scan (offs/toff/cur_rel).
// Blocks 197..912: weight transform (716 blocks = 183296 threads, covers T3):
//   W1Tb [19][64][128]; W2Tb [19][16][64] (cols>=2 zero); loop1Tb [64][128].
__global__ __launch_bounds__(256) void k_alloc_scan(
    const int* __restrict__ hist_dst, int* __restrict__ dstart,
    int* __restrict__ cur_dst, int* __restrict__ gcnt,
    const int* __restrict__ hist_rel, int* __restrict__ offs,
    int* __restrict__ toff, int* __restrict__ cur_rel,
    const float* __restrict__ W1, const float* __restrict__ loop1,
    const float* __restrict__ W2, u16* __restrict__ W1Tb,
    u16* __restrict__ loop1Tb, u16* __restrict__ W2Tb){
  if (blockIdx.x >= 197) {                      // ---- weight transform ----
    int idx = (blockIdx.x - 197) * 256 + threadIdx.x;
    const int T1 = N_RELS * D_HID * D_IN;       // 155648
    const int T2 = T1 + N_RELS * 16 * D_HID;    // 175104
    const int T3 = T2 + D_HID * D_IN;           // 183296
    if (idx < T1) {
      int r = idx / (D_HID * D_IN);
      int t = idx - r * (D_HID * D_IN);
      int j = t >> 7, d = t & 127;
      W1Tb[idx] = f2bf(W1[(r * D_IN + d) * D_HID + j]);
    } else if (idx < T2) {
      int k2 = idx - T1;
      int r = k2 / (16 * D_HID);
      int t = k2 - r * (16 * D_HID);
      int n = t >> 6, k = t & 63;
      W2Tb[k2] = (n < D_OUT) ? f2bf(W2[(r * D_HID + k) * D_OUT + n]) : (u16)0;
    } else if (idx < T3) {
      int k2 = idx - T2;
      int j = k2 >> 7, d = k2 & 127;
      loop1Tb[k2] = f2bf(loop1[d * D_HID + j]);
    }
    return;
  }
  if (blockIdx.x == 196) {                      // ---- rel scan ----
    if (threadIdx.x == 0) {
      int acc = 0, tacc = 0;
      offs[0] = 0; toff[0] = 0;
      for (int r = 0; r < N_RELS; ++r) {
        cur_rel[r] = acc;
        int c = hist_rel[r];
        acc += c;                offs[r + 1] = acc;
        tacc += (c + 127) >> 7;  toff[r + 1] = tacc;
      }
    }
    return;
  }
  // ---- dst region allocation ----
  __shared__ int wbase[4];
  int tid = threadIdx.x, lane = tid & 63, wv = tid >> 6;
  int n = blockIdx.x * 256 + tid;
  int v = (n < N_NODES) ? hist_dst[n] : 0;
  int x = v;
  #pragma unroll
  for (int o = 1; o < 64; o <<= 1) { int u = __shfl_up(x, o); if (lane >= o) x += u; }
  if (lane == 63) wbase[wv] = atomicAdd(gcnt, x);   // x = wave total
  __syncthreads();
  int start = wbase[wv] + x - v;
  if (n < N_NODES) { dstart[n] = start; cur_dst[n] = start; }
}

__global__ __launch_bounds__(256) void k_scatter_rel(const int* __restrict__ et,
                                                     int* __restrict__ cursor,
                                                     int* __restrict__ perm){
  __shared__ int lh[N_RELS], base[N_RELS];
  int tid = threadIdx.x;
  if (tid < N_RELS) lh[tid] = 0;
  __syncthreads();
  int e = blockIdx.x * 256 + tid;
  int r = 0, my = 0;
  bool valid = e < N_EDGES;
  if (valid) { r = et[e]; my = atomicAdd(&lh[r], 1); }
  __syncthreads();
  if (tid < N_RELS && lh[tid]) base[tid] = atomicAdd(&cursor[tid], lh[tid]);
  __syncthreads();
  if (valid) perm[base[r] + my] = e;
}

// Merged: blocks < EDGE_TILES run layer-1 edge tiles (128 edges, K=128 bf16 MFMA,
// B staged in LDS, messages -> msgbuf rows). Blocks >= EDGE_TILES run the dense
// self-loop GEMM (agg1f = feat @ loop1 + b1), also with B staged in LDS.
__global__ __launch_bounds__(256) void k_se1(
    const u16* __restrict__ featb, const u16* __restrict__ W1Tb,
    const u16* __restrict__ loop1Tb, const float* __restrict__ b1,
    const int* __restrict__ src, const int* __restrict__ dst,
    const int* __restrict__ perm, const int* __restrict__ offs,
    const int* __restrict__ toff, int* __restrict__ cur_dst,
    u16* __restrict__ msgbuf, float* __restrict__ agg1f){
  __shared__ __align__(16) u16 Als[128][136];   // 34816 B; overlaid by msg fp32 [128][68]
  __shared__ __align__(16) u16 Bls[64][136];    // 17408 B
  __shared__ int posIds[128];
  int tid = threadIdx.x, lane = tid & 63, w = tid >> 6;
  int r16 = lane & 15, c4 = lane >> 4;

  if (blockIdx.x >= EDGE_TILES) {               // ---- self-loop path ----
    int base = (blockIdx.x - EDGE_TILES) * 64;
    { int j = tid >> 2, seg = tid & 3;
      const uint4* g = (const uint4*)(loop1Tb + j * 128) + seg * 4;
      uint4* d = (uint4*)&Bls[j][seg * 32];
      d[0] = g[0]; d[1] = g[1]; d[2] = g[2]; d[3] = g[3]; }
    { int i = tid >> 2, seg = tid & 3;
      int n = base + i; if (n >= N_NODES) n = N_NODES - 1;
      const uint4* g = (const uint4*)(featb + (size_t)n * D_IN) + seg * 4;
      uint4* d = (uint4*)&Als[i][seg * 32];
      d[0] = g[0]; d[1] = g[1]; d[2] = g[2]; d[3] = g[3]; }
    __syncthreads();
    sfrag aF[4];
    #pragma unroll
    for (int kk = 0; kk < 4; ++kk)
      aF[kk] = *(const sfrag*)&Als[w * 16 + r16][kk * 32 + c4 * 8];
    #pragma unroll
    for (int ct = 0; ct < 4; ++ct) {
      f32x4 acc = {0.f, 0.f, 0.f, 0.f};
      #pragma unroll
      for (int kk = 0; kk < 4; ++kk) {
        sfrag bF = *(const sfrag*)&Bls[ct * 16 + r16][kk * 32 + c4 * 8];
        acc = __builtin_amdgcn_mfma_f32_16x16x32_bf16(aF[kk], bF, acc, 0, 0, 0);
      }
      int col = ct * 16 + r16;
      float bias = b1[col];
      #pragma unroll
      for (int reg = 0; reg < 4; ++reg) {
        int row = base + w * 16 + c4 * 4 + reg;
        if (row < N_NODES) agg1f[(size_t)row * D_HID + col] = acc[reg] + bias;
      }
    }
    return;
  }

  // ---- edge-tile path ----
  int b = blockIdx.x;
  unsigned long long mm = __ballot((lane < N_RELS) && (b >= toff[lane + 1]));
  int rel = __popcll(mm);
  if (rel >= N_RELS) return;                    // uniform pad-tile exit
  int ts = offs[rel] + ((b - toff[rel]) << 7);
  int vc = offs[rel + 1] - ts; if (vc > 128) vc = 128;

  { // B tile: W1Tb[rel], 64 x 128 bf16 (16 KB)
    int j = tid >> 2, seg = tid & 3;
    const uint4* g = (const uint4*)(W1Tb + ((size_t)rel * 64 + j) * 128) + seg * 4;
    uint4* d = (uint4*)&Bls[j][seg * 32];
    d[0] = g[0]; d[1] = g[1]; d[2] = g[2]; d[3] = g[3];
  }
  // A tile: 128 rows x 256 B, 2 passes, 4 threads/row
  #pragma unroll
  for (int p = 0; p < 2; ++p) {
    int i = p * 64 + (tid >> 2), seg = tid & 3;
    if (i < vc) {
      int e = perm[ts + i];
      if (seg == 0) posIds[i] = atomicAdd(&cur_dst[dst[e]], 1);  // absolute msg row
      const uint4* g = (const uint4*)(featb + (size_t)src[e] * D_IN) + seg * 4;
      uint4* d = (uint4*)&Als[i][seg * 32];
      d[0] = g[0]; d[1] = g[1]; d[2] = g[2]; d[3] = g[3];
    } else if (seg == 0) posIds[i] = -1;
  }
  __syncthreads();

  sfrag aF[2][4];
  #pragma unroll
  for (int mt = 0; mt < 2; ++mt)
    #pragma unroll
    for (int kk = 0; kk < 4; ++kk)
      aF[mt][kk] = *(const sfrag*)&Als[w * 32 + mt * 16 + r16][kk * 32 + c4 * 8];
  f32x4 accAll[2][4];
  #pragma unroll
  for (int ct = 0; ct < 4; ++ct) {
    sfrag bF[4];
    #pragma unroll
    for (int kk = 0; kk < 4; ++kk)
      bF[kk] = *(const sfrag*)&Bls[ct * 16 + r16][kk * 32 + c4 * 8];
    #pragma unroll
    for (int mt = 0; mt < 2; ++mt) {
      f32x4 acc = {0.f, 0.f, 0.f, 0.f};
      #pragma unroll
      for (int kk = 0; kk < 4; ++kk)
        acc = __builtin_amdgcn_mfma_f32_16x16x32_bf16(aF[mt][kk], bF[kk], acc, 0, 0, 0);
      accAll[mt][ct] = acc;
    }
  }
  // msg overlay (wave-private rows), then coalesced bf16 row write-out
  float* msg = (float*)&Als[0][0];              // stride 68 floats == 272 B == Als row
  #pragma unroll
  for (int mt = 0; mt < 2; ++mt)
    #pragma unroll
    for (int ct = 0; ct < 4; ++ct) {
      int col = ct * 16 + r16;
      #pragma unroll
      for (int reg = 0; reg < 4; ++reg) {
        int row = w * 32 + mt * 16 + c4 * 4 + reg;   // D: col=lane&15, row=(lane>>4)*4+reg
        msg[row * 68 + col] = accAll[mt][ct][reg];
      }
    }
  __syncthreads();
  { int row = tid >> 1, half = tid & 1;
    int pos = posIds[row];
    if (pos >= 0) {
      const float* mr = msg + row * 68 + half * 32;
      u32 pk[16];
      #pragma unroll
      for (int q = 0; q < 16; ++q)
        pk[q] = (u32)f2bf(mr[2 * q]) | ((u32)f2bf(mr[2 * q + 1]) << 16);
      uint4* d = (uint4*)(msgbuf + (size_t)pos * D_HID + half * 32);
      d[0] = *(uint4*)&pk[0];  d[1] = *(uint4*)&pk[4];
      d[2] = *(uint4*)&pk[8];  d[3] = *(uint4*)&pk[12];
    } }
}

// Fused: message aggregation (one node per wave) + self-loop + relu -> h1b,
// plus layer-2 self-loop: out[n,:] = h1 @ loop2 + b2 (full init of out).
__global__ __launch_bounds__(256) void k_agg_relu_self2(
    const u16* __restrict__ msgbuf, const int* __restrict__ dstart,
    const int* __restrict__ cnt, const float* __restrict__ agg1f,
    const float* __restrict__ loop2, const float* __restrict__ b2,
    u16* __restrict__ h1b, float* __restrict__ out){
  int wv = threadIdx.x >> 6, lane = threadIdx.x & 63;
  int n = blockIdx.x * 4 + wv;
  int s = dstart[n], epos = s + cnt[n];
  int h = lane >> 5, c = lane & 31;
  float a0 = 0.f, a1 = 0.f;
  for (int i = s + h; i < epos; i += 2) {
    u32 v = ((const u32*)msgbuf)[(size_t)i * 32 + c];
    a0 += bf2f((u16)(v & 0xffffu));
    a1 += bf2f((u16)(v >> 16));
  }
  a0 += __shfl_down(a0, 32);
  a1 += __shfl_down(a1, 32);
  float p0 = 0.f, p1 = 0.f;
  if (h == 0) {
    float2 sl = ((const float2*)(agg1f + (size_t)n * D_HID))[c];
    float v0 = a0 + sl.x, v1 = a1 + sl.y;
    v0 = v0 > 0.f ? v0 : 0.f;
    v1 = v1 > 0.f ? v1 : 0.f;
    ((u32*)h1b)[(size_t)n * 32 + c] = (u32)f2bf(v0) | ((u32)f2bf(v1) << 16);
    float2 w0 = ((const float2*)loop2)[2 * c];
    float2 w1 = ((const float2*)loop2)[2 * c + 1];
    p0 = v0 * w0.x + v1 * w1.x;
    p1 = v0 * w0.y + v1 * w1.y;
  }
  #pragma unroll
  for (int off = 16; off; off >>= 1) {
    p0 += __shfl_down(p0, off);
    p1 += __shfl_down(p1, off);
  }
  if (lane == 0) {
    out[n * 2]     = p0 + b2[0];
    out[n * 2 + 1] = p1 + b2[1];
  }
}

// Layer-2 edge messages: 128-edge rel-pure tiles, K=64 bf16 MFMA, cheap 2-col atomics.
__global__ __launch_bounds__(256) void k_edge2_mfma(
    const u16* __restrict__ h1b, const u16* __restrict__ W2Tb,
    const int* __restrict__ src, const int* __restrict__ dst,
    const int* __restrict__ perm, const int* __restrict__ offs,
    const int* __restrict__ toff, float* __restrict__ out){
  __shared__ __align__(16) u16 Als[128][72];
  __shared__ __align__(16) u16 Bls[16][72];
  __shared__ int dstIds[128];
  int tid = threadIdx.x, lane = tid & 63, w = tid >> 6;

  int b = blockIdx.x;
  unsigned long long mm = __ballot((lane < N_RELS) && (b >= toff[lane + 1]));
  int rel = __popcll(mm);
  if (rel >= N_RELS) return;
  int ts = offs[rel] + ((b - toff[rel]) << 7);
  int vc = offs[rel + 1] - ts; if (vc > 128) vc = 128;

  if (tid < 128) {   // B tile: 16 x 64 bf16 = 128 uint4
    ((uint4*)&Bls[tid >> 3][0])[tid & 7] = ((const uint4*)(W2Tb + (size_t)rel * 16 * 64))[tid];
  }
  { // A: 128 rows x 128 B, 2 threads/row
    int i = tid >> 1, half = tid & 1;
    if (i < vc) {
      int e = perm[ts + i];
      if (half == 0) dstIds[i] = dst[e];
      const uint4* g = (const uint4*)(h1b + (size_t)src[e] * D_HID) + half * 4;
      uint4* d = (uint4*)&Als[i][half * 32];
      d[0] = g[0]; d[1] = g[1]; d[2] = g[2]; d[3] = g[3];
    } else if (half == 0) dstIds[i] = -1;
  }
  __syncthreads();

  int r16 = lane & 15, c4 = lane >> 4;
  #pragma unroll
  for (int mt = 0; mt < 2; ++mt) {
    f32x4 acc = {0.f, 0.f, 0.f, 0.f};
    #pragma unroll
    for (int kk = 0; kk < 2; ++kk) {
      sfrag aF = *(const sfrag*)&Als[w * 32 + mt * 16 + r16][kk * 32 + c4 * 8];
      sfrag bF = *(const sfrag*)&Bls[r16][kk * 32 + c4 * 8];
      acc = __builtin_amdgcn_mfma_f32_16x16x32_bf16(aF, bF, acc, 0, 0, 0);
    }
    if (r16 < D_OUT) {
      #pragma unroll
      for (int reg = 0; reg < 4; ++reg) {
        int row = w * 32 + mt * 16 + c4 * 4 + reg;
        int dn = dstIds[row];
        if (dn >= 0) atomicAdd(&out[dn * D_OUT + r16], acc[reg]);
      }
    }
  }
}

extern "C" void kernel_launch(void* const* d_in, const int* in_sizes, int n_in,
                              void* d_out, int out_size, void* d_ws, size_t ws_size,
                              hipStream_t stream){
  const float* feat  = (const float*)d_in[0];
  const float* W1    = (const float*)d_in[1];
  const float* loop1 = (const float*)d_in[2];
  const float* b1    = (const float*)d_in[3];
  const float* W2    = (const float*)d_in[4];
  const float* loop2 = (const float*)d_in[5];
  const float* b2    = (const float*)d_in[6];
  const int* src     = (const int*)d_in[7];
  const int* dst     = (const int*)d_in[8];
  const int* et      = (const int*)d_in[9];
  float* out = (float*)d_out;

  // workspace layout (16B-aligned), ~112 MB total.
  // hist_rel/gcnt/hist_dst are contiguous -> single memset zeroes all three.
  char* w = (char*)d_ws;
  u16*   W1Tb     = (u16*)(w);                   //  311296
  u16*   W2Tb     = (u16*)(w + 311296);          //   38912
  u16*   loop1Tb  = (u16*)(w + 350208);          //   16384
  int*   hist_rel = (int*)(w + 366592);          //     128 ┐
  int*   gcnt     = (int*)(w + 366720);          //     128 ├ zeroed by memset (200256 B)
  int*   hist_dst = (int*)(w + 366848);          //  200000 ┘
  int*   offs     = (int*)(w + 566848);          //     128
  int*   toff     = (int*)(w + 566976);          //     128
  int*   cur_rel  = (int*)(w + 567104);          //     128
  int*   dstart   = (int*)(w + 567232);          //  200000
  int*   cur_dst  = (int*)(w + 767232);          //  200000
  int*   perm     = (int*)(w + 967232);          // 2400000
  u16*   featb    = (u16*)(w + 3367232);         // 12.8 MB
  float* agg1f    = (float*)(w + 16167232);      // 12.8 MB
  u16*   h1b      = (u16*)(w + 28967232);        //  6.4 MB
  u16*   msgbuf   = (u16*)(w + 35367232);        // 76.8 MB -> 112167232

  hipMemsetAsync(w + 366592, 0, 200256, stream);
  k_fused_pre     <<<12500, 256, 0, stream>>>(feat, featb, et, dst, hist_rel, hist_dst);
  k_alloc_scan    <<<197 + PREP_BLOCKS, 256, 0, stream>>>(
                      hist_dst, dstart, cur_dst, gcnt, hist_rel, offs, toff, cur_rel,
                      W1, loop1, W2, W1Tb, loop1Tb, W2Tb);
  k_scatter_rel   <<<2344,  256, 0, stream>>>(et, cur_rel, perm);
  k_se1           <<<EDGE_TILES + SL_BLOCKS, 256, 0, stream>>>(
                      featb, W1Tb, loop1Tb, b1, src, dst, perm, offs, toff,
                      cur_dst, msgbuf, agg1f);
  k_agg_relu_self2<<<12500, 256, 0, stream>>>(msgbuf, dstart, hist_dst, agg1f,
                                              loop2, b2, h1b, out);
  k_edge2_mfma    <<<EDGE_TILES, 256, 0, stream>>>(h1b, W2Tb, src, dst, perm, offs, toff, out);
}